// Round 2
// baseline (99.803 us; speedup 1.0000x reference)
//
#include <hip/hip_runtime.h>

// Round 8: 16 waves x 64 (1024 thr), 16-query strips, pair (w, 31-w).
// Theory: R6/R7 identical at 45us kernel with MfmaUtil 9% / VALUBusy 16% /
// Occupancy 17.5% -> latency-bound at 2 waves/SIMD; the wall is each wave's
// serial chain (17 tiles of 32q work + full-size projection phases), which
// the compiler re-serialized when we tried intra-wave dual-tile ILP (VGPR=96).
// R8 halves every wave's chain at WAVE granularity (can't be rescheduled
// away): 32 strips of 16 queries, wave w owns {w, 31-w} = 17 key tiles with
// 4 QK MFMA + 8 exp + 4 PV MFMA per tile; PB projects 32 tokens/wave; PA one
// 16-row make_qf per strip. Occupancy 2 -> 4 waves/SIMD (128-VGPR cap via
// __launch_bounds__(1024,4); structure sized to ~105 live regs, no spill).
// Same total FLOPs, same K/V frag-image layouts, same LDS footprint (128KB).

#define SEQ 512
#define CH  64

#define SLOT_STRIDE 72                    // padded Q-transpose slot row (shorts)
#define SLOT_SIZE   (16 * SLOT_STRIDE)    // 1152 shorts per wave slot
#define WOFF        (16 * SLOT_SIZE)      // weight frag images at ldsK + 18432

typedef __attribute__((ext_vector_type(8))) short bf16x8;
typedef __attribute__((ext_vector_type(4))) short bf16x4;
typedef __attribute__((ext_vector_type(4))) float f32x4;

static __device__ __forceinline__ short f2bf(float f) {
  union { float f; unsigned u; } v; v.f = f;
  unsigned r = v.u + 0x7FFFu + ((v.u >> 16) & 1u);   // RNE
  return (short)(r >> 16);
}

static __device__ __forceinline__ bf16x4 pack4(f32x4 v) {
  bf16x4 r;
  r[0] = f2bf(v[0]); r[1] = f2bf(v[1]); r[2] = f2bf(v[2]); r[3] = f2bf(v[3]);
  return r;
}

static __device__ __forceinline__ f32x4 mfma32(bf16x8 a, bf16x8 b, f32x4 c) {
  return __builtin_amdgcn_mfma_f32_16x16x32_bf16(a, b, c, 0, 0, 0);
}

// pack two f32 -> bf16x2 dword by truncation (1 VALU)
static __device__ __forceinline__ unsigned pperm(float hi, float lo) {
#if defined(__has_builtin) && __has_builtin(__builtin_amdgcn_perm)
  return __builtin_amdgcn_perm(__builtin_bit_cast(unsigned, hi),
                               __builtin_bit_cast(unsigned, lo), 0x07060302u);
#else
  return (__builtin_bit_cast(unsigned, hi) & 0xFFFF0000u) |
         (__builtin_bit_cast(unsigned, lo) >> 16);
#endif
}

#if defined(__has_builtin) && __has_builtin(__builtin_amdgcn_exp2f)
#define EXP2(v) __builtin_amdgcn_exp2f(v)
#else
#define EXP2(v) __expf((v) * 0.6931471805599453f)
#endif

static __device__ __forceinline__ void wave_lds_fence() {
  asm volatile("s_waitcnt lgkmcnt(0)" ::: "memory");
}

// Q fragments for one 16-row strip via the wave-private padded slot.
static __device__ __forceinline__ void make_qf16(
    const float* __restrict__ xb, const bf16x8 WQf[4][2],
    unsigned short* slot, int q0, int l15, int quad, bf16x8 qf[2]) {
  bf16x8 xa[2];
#pragma unroll
  for (int c = 0; c < 2; ++c) {
    const float* px = xb + (size_t)(q0 + l15) * CH + c * 32 + quad * 8;
    float4 lo = *(const float4*)px;
    float4 hi = *(const float4*)(px + 4);
    bf16x8 f;
    f[0] = f2bf(lo.x); f[1] = f2bf(lo.y); f[2] = f2bf(lo.z); f[3] = f2bf(lo.w);
    f[4] = f2bf(hi.x); f[5] = f2bf(hi.y); f[6] = f2bf(hi.z); f[7] = f2bf(hi.w);
    xa[c] = f;
  }
#pragma unroll
  for (int cht = 0; cht < 4; ++cht) {
    f32x4 qt = {0.f, 0.f, 0.f, 0.f};
#pragma unroll
    for (int c = 0; c < 2; ++c)
      qt = mfma32(WQf[cht][c], xa[c], qt);   // Q^T[16cht+4q+r][q0+l15]
    *(bf16x4*)(slot + l15 * SLOT_STRIDE + cht * 16 + quad * 4) = pack4(qt);
  }
  wave_lds_fence();
#pragma unroll
  for (int c = 0; c < 2; ++c)
    qf[c] = *(const bf16x8*)(slot + l15 * SLOT_STRIDE + c * 32 + quad * 8);
  wave_lds_fence();   // drain reads before slot is overwritten
}

// One 16-query strip s (queries [16s, 16s+16)): key tiles 0..(s>>1), the last
// one diagonal with parity-dependent masking.
static __device__ __forceinline__ void run_strip16(
    int s, const bf16x8 qf[2], const unsigned short* __restrict__ ldsK,
    const unsigned short* __restrict__ ldsV, float* __restrict__ outb,
    int lane, int l15, int quad) {
  const int q0  = s * 16;
  const int nd  = s >> 1;       // number of full tiles before the diagonal
  const int odd = s & 1;
  f32x4 ot[4];
#pragma unroll
  for (int cht = 0; cht < 4; ++cht) ot[cht] = (f32x4){0.f, 0.f, 0.f, 0.f};
  float ls = 0.f;
  const int dthr = l15 - quad * 4;

  bf16x8 kf[4];
#pragma unroll
  for (int i = 0; i < 4; ++i)
    kf[i] = *(const bf16x8*)(ldsK + i * 512 + lane * 8);   // tile 0

#pragma unroll 1
  for (int t = 0; t < nd; ++t) {
    // V for this tile + K prefetch for the next
    bf16x8 vf[4], kn[4];
    const unsigned short* vp = ldsV + t * 2048;
    const unsigned short* kp = ldsK + (t + 1) * 2048;
#pragma unroll
    for (int i = 0; i < 4; ++i) {
      vf[i] = *(const bf16x8*)(vp + i * 512 + lane * 8);
      kn[i] = *(const bf16x8*)(kp + i * 512 + lane * 8);
    }

    // S^T subtiles: s0 = keys 32t..+15, s1 = keys 32t+16..+31, cols q0+l15
    f32x4 s0 = {0.f,0.f,0.f,0.f}, s1 = {0.f,0.f,0.f,0.f};
    s0 = mfma32(kf[0], qf[0], s0); s0 = mfma32(kf[1], qf[1], s0);
    s1 = mfma32(kf[2], qf[0], s1); s1 = mfma32(kf[3], qf[1], s1);

    union { bf16x8 v; unsigned u[4]; } P;
#pragma unroll
    for (int r = 0; r < 4; ++r) {
      s0[r] = EXP2(s0[r]);  ls += s0[r];
      s1[r] = EXP2(s1[r]);  ls += s1[r];
    }
    P.u[0] = pperm(s0[1], s0[0]); P.u[1] = pperm(s0[3], s0[2]);
    P.u[2] = pperm(s1[1], s1[0]); P.u[3] = pperm(s1[3], s1[2]);

    // O^T += V^T . P^T  (key permutation baked into the V image order)
    ot[0] = mfma32(vf[0], P.v, ot[0]);
    ot[1] = mfma32(vf[1], P.v, ot[1]);
    ot[2] = mfma32(vf[2], P.v, ot[2]);
    ot[3] = mfma32(vf[3], P.v, ot[3]);

#pragma unroll
    for (int i = 0; i < 4; ++i) kf[i] = kn[i];
  }

  // ---- diagonal tile nd
  {
    bf16x8 vf[4];
    const unsigned short* vp = ldsV + (size_t)nd * 2048;
#pragma unroll
    for (int i = 0; i < 4; ++i)
      vf[i] = *(const bf16x8*)(vp + i * 512 + lane * 8);

    f32x4 s0 = {0.f,0.f,0.f,0.f}, s1 = {0.f,0.f,0.f,0.f};
    s0 = mfma32(kf[0], qf[0], s0); s0 = mfma32(kf[1], qf[1], s0);
    if (odd) { s1 = mfma32(kf[2], qf[0], s1); s1 = mfma32(kf[3], qf[1], s1); }

    union { bf16x8 v; unsigned u[4]; } P;
    if (odd) {
      // queries rel 16+l15: keys 0-15 never masked, keys 16-31 masked r>dthr
#pragma unroll
      for (int r = 0; r < 4; ++r) {
        s0[r] = EXP2(s0[r]);                       ls += s0[r];
        s1[r] = (r > dthr) ? 0.f : EXP2(s1[r]);    ls += s1[r];
      }
      P.u[0] = pperm(s0[1], s0[0]); P.u[1] = pperm(s0[3], s0[2]);
      P.u[2] = pperm(s1[1], s1[0]); P.u[3] = pperm(s1[3], s1[2]);
    } else {
      // queries rel l15: keys 0-15 masked r>dthr, keys 16-31 fully masked
#pragma unroll
      for (int r = 0; r < 4; ++r) {
        s0[r] = (r > dthr) ? 0.f : EXP2(s0[r]);    ls += s0[r];
      }
      P.u[0] = pperm(s0[1], s0[0]); P.u[1] = pperm(s0[3], s0[2]);
      P.u[2] = 0u; P.u[3] = 0u;
    }
    ot[0] = mfma32(vf[0], P.v, ot[0]);
    ot[1] = mfma32(vf[1], P.v, ot[1]);
    ot[2] = mfma32(vf[2], P.v, ot[2]);
    ot[3] = mfma32(vf[3], P.v, ot[3]);
  }

  // column sums live across the 4 quads
  ls += __shfl_xor(ls, 16); ls += __shfl_xor(ls, 32);
  const float inv = 1.0f / ls;

#pragma unroll
  for (int cht = 0; cht < 4; ++cht) {
    float4 v;
    v.x = ot[cht][0] * inv; v.y = ot[cht][1] * inv;
    v.z = ot[cht][2] * inv; v.w = ot[cht][3] * inv;
    *(float4*)(outb + (size_t)(q0 + l15) * CH + cht * 16 + quad * 4) = v;
  }
}

__global__ __launch_bounds__(1024, 4)
void attn_fused(const float* __restrict__ x,
                const float* __restrict__ wk,
                const float* __restrict__ wq,
                const float* __restrict__ wv,
                float* __restrict__ out) {
  // ldsK: finally the K frag image (64 KB); before that, overlaid:
  //   [0, 18432)        16 wave-private padded Q-transpose slots (36 KB)
  //   [18432, 30720)    24 weight frag images, 512 shorts each (24 KB)
  // ldsV: V frag image (64 KB), written in phase B only.
  __shared__ alignas(16) unsigned short ldsK[SEQ * CH];
  __shared__ alignas(16) unsigned short ldsV[SEQ * CH];

  const int b    = blockIdx.x;
  const int w    = threadIdx.x >> 6;   // wave 0..15
  const int lane = threadIdx.x & 63;
  const int l15  = lane & 15;
  const int quad = lane >> 4;

  const float* xb   = x + (size_t)b * SEQ * CH;
  float*       outb = out + (size_t)b * SEQ * CH;

  // ---- P0: cooperative weight frag-image build. 24 jobs (3 matrices x 8
  // chunks); wave w does job w, waves 0..7 additionally job 16+w.
  {
#pragma unroll
    for (int pass = 0; pass < 2; ++pass) {
      const int j = pass ? (16 + w) : w;
      if (pass && w >= 8) break;
      const int m  = j >> 3, wc = j & 7;
      const int t  = wc >> 1, c = wc & 1;
      const int k0 = c * 32 + quad * 8;
      const int n  = t * 16 + l15;
      const float* Wsrc  = (m == 0) ? wq : (m == 1) ? wk : wv;
      const float  scale = (m == 0) ? 0.18033688011112042f : 1.0f;  // C^-0.5*log2e
      bf16x8 fr;
#pragma unroll
      for (int jj = 0; jj < 8; ++jj)
        fr[jj] = f2bf(Wsrc[(k0 + jj) * CH + n] * scale);
      *(bf16x8*)(ldsK + WOFF + (m * 8 + wc) * 512 + lane * 8) = fr;
    }
  }
  __syncthreads();

  // ---- PA: Q fragments for 16-row strips {w, 31-w}
  const int sA = w, sB = 31 - w;
  unsigned short* slot = ldsK + w * SLOT_SIZE;
  bf16x8 qfA[2], qfB[2];
  {
    bf16x8 WQf[4][2];
#pragma unroll
    for (int t = 0; t < 4; ++t)
#pragma unroll
      for (int c = 0; c < 2; ++c)
        WQf[t][c] = *(const bf16x8*)(ldsK + WOFF + (t * 2 + c) * 512 + lane * 8);
    make_qf16(xb, WQf, slot, sA * 16, l15, quad, qfA);
    make_qf16(xb, WQf, slot, sB * 16, l15, quad, qfB);
  }

  // ---- PB: K,V frag images; wave w projects tokens [32w, 32w+32)
  {
    bf16x8 WKf[4][2], WVf[4][2];
#pragma unroll
    for (int t = 0; t < 4; ++t)
#pragma unroll
      for (int c = 0; c < 2; ++c) {
        WKf[t][c] = *(const bf16x8*)(ldsK + WOFF + (8  + t * 2 + c) * 512 + lane * 8);
        WVf[t][c] = *(const bf16x8*)(ldsK + WOFF + (16 + t * 2 + c) * 512 + lane * 8);
      }
    __syncthreads();   // slots + weight area free before K image overwrites them

#pragma unroll
    for (int sub = 0; sub < 2; ++sub) {
      const int t16 = w * 32 + sub * 16;
      bf16x8 xa[2];
#pragma unroll
      for (int c = 0; c < 2; ++c) {
        const float* px = xb + (size_t)(t16 + l15) * CH + c * 32 + quad * 8;
        float4 lo = *(const float4*)px;
        float4 hi = *(const float4*)(px + 4);
        bf16x8 f;
        f[0] = f2bf(lo.x); f[1] = f2bf(lo.y); f[2] = f2bf(lo.z); f[3] = f2bf(lo.w);
        f[4] = f2bf(hi.x); f[5] = f2bf(hi.y); f[6] = f2bf(hi.z); f[7] = f2bf(hi.w);
        xa[c] = f;
      }
#pragma unroll
      for (int cht = 0; cht < 4; ++cht) {   // K^T C-frags -> frag-image store
        f32x4 ak = {0.f, 0.f, 0.f, 0.f};
#pragma unroll
        for (int c = 0; c < 2; ++c)
          ak = mfma32(WKf[cht][c], xa[c], ak);
        const int cdst = cht >> 1;
        const int qp   = ((cht & 1) << 1) | (quad >> 1);
        *(bf16x4*)(ldsK + (t16 >> 4) * 1024 + cdst * 512 +
                   (qp * 16 + l15) * 8 + (quad & 1) * 4) = pack4(ak);
      }
#pragma unroll
      for (int nt = 0; nt < 4; ++nt) {      // V C-frags -> key-permuted V^T image
        f32x4 av = {0.f, 0.f, 0.f, 0.f};
#pragma unroll
        for (int c = 0; c < 2; ++c)
          av = mfma32(xa[c], WVf[nt][c], av);
        *(bf16x4*)(ldsV + (t16 >> 5) * 2048 + nt * 512 +
                   (quad * 16 + l15) * 8 + ((t16 >> 4) & 1) * 4) = pack4(av);
      }
    }
  }
  __syncthreads();

  // ---- PC: two balanced 16-row strips = exactly 17 key-tile iterations/wave
  run_strip16(sA, qfA, ldsK, ldsV, outb, lane, l15, quad);
  run_strip16(sB, qfB, ldsK, ldsV, outb, lane, l15, quad);
}

extern "C" void kernel_launch(void* const* d_in, const int* in_sizes, int n_in,
                              void* d_out, int out_size, void* d_ws, size_t ws_size,
                              hipStream_t stream) {
  const float* x  = (const float*)d_in[0];
  const float* wk = (const float*)d_in[1];   // w_key
  const float* wq = (const float*)d_in[2];   // w_query
  const float* wv = (const float*)d_in[3];   // w_value
  (void)in_sizes; (void)n_in; (void)out_size; (void)d_ws; (void)ws_size;
  attn_fused<<<256, 1024, 0, stream>>>(x, wk, wq, wv, (float*)d_out);
}